// Round 34
// baseline (536.142 us; speedup 1.0000x reference)
//
#include <hip/hip_runtime.h>
#include <hip/hip_bf16.h>
#include <math.h>

#define B_ 4
#define N_ 16384
#define M_ 4096
#define K_ 16
#define C_ 128
#define OUT_ 256
#define S_CHUNKS 16
#define CHUNK 1024
#define TPB 256
#define MAX_R 0.3f
#define BIGF 1e9f
#define LN_EPS_F 1e-5f
#define SEPS 1e-6f
#define BM (B_ * M_)

// KNN exactness (r25, FROZEN): d2 = fma(-2,dot,aq+bq), sq=(x²+z²)+y²,
// dot=fma(c2p2,fma(c1p1,c0p0)), dist=sqrt(d2+eps)<=0.3, (dist,idx) stable.
// r34: A hot loop pays sqrt+mask+append on every candidate (68 insts/iter).
// Conservative d2 PRETEST: v15q = min(0.0905, v15²+1e-6); only d2 < v15q
// enters the exact path. Proof: md=sqrt_rn(d2+1e-6)<v15 => d2 < v15²+1e-6;
// prefill covered by 0.0905 >= d2 of any dist<=0.3. Extra passes harmless.

typedef __attribute__((ext_vector_type(8))) short bf16x8;
typedef __attribute__((ext_vector_type(4))) float f32x4;

__device__ __forceinline__ unsigned short bfu(float f) {
  __hip_bfloat16 h = __float2bfloat16(f);
  return *reinterpret_cast<unsigned short*>(&h);
}
__device__ __forceinline__ float b2f(unsigned short u) {
  unsigned x = ((unsigned)u) << 16;
  return __uint_as_float(x);
}

// ---------------------------------------------------------------------------
// Kernel A: per-(center, chunk) partial top-16, deferred buffer + d2 pretest
// ---------------------------------------------------------------------------
__global__ __launch_bounds__(TPB) void knn_partial_kernel(
    const float* __restrict__ points, const int* __restrict__ cidx,
    float* __restrict__ pvals, int* __restrict__ pidx)
{
#pragma clang fp contract(off)
  const int s  = blockIdx.x;
  const int mg = blockIdx.y;
  const int b  = blockIdx.z;
  const int tid = threadIdx.x;

  __shared__ float4 pts[CHUNK];
  __shared__ unsigned long long buf[8][TPB];

  const int j0 = s * CHUNK;
  for (int e = tid; e < CHUNK; e += TPB) {
    int j = j0 + e;
    float x = points[(b * N_ + j) * 3 + 0];
    float y = points[(b * N_ + j) * 3 + 1];
    float z = points[(b * N_ + j) * 3 + 2];
    float bq = (x * x + z * z) + y * y;      // einsum SSE2 tree
    pts[e] = make_float4(x, y, z, bq);
  }

  const int m  = mg * TPB + tid;
  const int cm = b * M_ + m;
  const int ci = cidx[cm];
  const float cx = points[(b * N_ + ci) * 3 + 0];
  const float cy = points[(b * N_ + ci) * 3 + 1];
  const float cz = points[(b * N_ + ci) * 3 + 2];
  const float aq = (cx * cx + cz * cz) + cy * cy;   // einsum SSE2 tree
  __syncthreads();

  float v[16];
  int   id[16];
#pragma unroll
  for (int t = 0; t < 16; t++) { v[t] = 3.4e38f; id[t] = 0; }
  float v15  = BIGF;
  float v15q = 0.0905f;   // conservative d2 gate (covers dist<=0.3 mask)
  int cnt = 0;

  for (int e = 0; e < CHUNK; e++) {
    float4 p = pts[e];
    float dot = fmaf(cz, p.z, fmaf(cy, p.y, cx * p.x));  // BLAS fma chain
    float d2 = fmaf(-2.0f, dot, aq + p.w);
    if (d2 < v15q) {                         // conservative pretest (cheap path)
      float d2c = fmaxf(d2, 0.0f);
      float dist = __fsqrt_rn(d2c + SEPS);
      float md = (dist <= MAX_R) ? dist : BIGF;
      if (md < v15) {
        buf[cnt][tid] =
            ((unsigned long long)__float_as_uint(md) << 32) | (unsigned)(j0 + e);
        cnt++;
      }
    }
    if (__any(cnt == 8)) {
      for (int ss = 0; ss < 8; ss++) {
        if (ss < cnt) {
          unsigned long long kk = buf[ss][tid];
          float mdd = __uint_as_float((unsigned)(kk >> 32));
          int j = (int)(kk & 0xffffffffULL);
          if (mdd < v[15]) {
            bool cg[16];
#pragma unroll
            for (int t = 0; t < 16; t++) cg[t] = (v[t] > mdd);
#pragma unroll
            for (int t = 15; t >= 1; t--) {
              v[t]  = cg[t - 1] ? v[t - 1]  : (cg[t] ? mdd : v[t]);
              id[t] = cg[t - 1] ? id[t - 1] : (cg[t] ? j   : id[t]);
            }
            if (cg[0]) { v[0] = mdd; id[0] = j; }
          }
        }
      }
      cnt = 0;
      v15 = fminf(v[15], BIGF);
      v15q = fminf(0.0905f, v15 * v15 + 1e-6f);
    }
  }

  for (int ss = 0; ss < 8; ss++) {
    if (ss < cnt) {
      unsigned long long kk = buf[ss][tid];
      float mdd = __uint_as_float((unsigned)(kk >> 32));
      int j = (int)(kk & 0xffffffffULL);
      if (mdd < v[15]) {
        bool cg[16];
#pragma unroll
        for (int t = 0; t < 16; t++) cg[t] = (v[t] > mdd);
#pragma unroll
        for (int t = 15; t >= 1; t--) {
          v[t]  = cg[t - 1] ? v[t - 1]  : (cg[t] ? mdd : v[t]);
          id[t] = cg[t - 1] ? id[t - 1] : (cg[t] ? j   : id[t]);
        }
        if (cg[0]) { v[0] = mdd; id[0] = j; }
      }
    }
  }

#pragma unroll
  for (int t = 0; t < 16; t++) {
    int o = (s * 16 + t) * BM + cm;
    pvals[o] = v[t];
    pidx[o]  = id[t];
  }
}

// ---------------------------------------------------------------------------
// Kernel B: merge S_CHUNKS sorted partial lists (64 thr/block, 256 blocks)
// ---------------------------------------------------------------------------
__global__ __launch_bounds__(64) void knn_merge_kernel(
    const float* __restrict__ pvals, const int* __restrict__ pidx,
    int* __restrict__ kidx, float* __restrict__ dout)
{
  const int cm = blockIdx.x * 64 + threadIdx.x;

  unsigned long long key[16];
#pragma unroll
  for (int t = 0; t < 16; t++) {
    int o = t * BM + cm;
    unsigned int vb = __float_as_uint(pvals[o]);
    key[t] = ((unsigned long long)vb << 32) | (unsigned int)pidx[o];
  }
  for (int s = 1; s < S_CHUNKS; s++) {
    for (int t2 = 0; t2 < 16; t2++) {
      int o = (s * 16 + t2) * BM + cm;
      unsigned int vb = __float_as_uint(pvals[o]);
      unsigned long long Kk = ((unsigned long long)vb << 32) | (unsigned int)pidx[o];
      if (Kk >= key[15]) break;
      bool cg[16];
#pragma unroll
      for (int t = 0; t < 16; t++) cg[t] = (key[t] > Kk);
#pragma unroll
      for (int t = 15; t >= 1; t--)
        key[t] = cg[t - 1] ? key[t - 1] : (cg[t] ? Kk : key[t]);
      if (cg[0]) key[0] = Kk;
    }
  }
#pragma unroll
  for (int t = 0; t < 16; t++) {
    int j = (int)(key[t] & 0xffffffffULL);
    kidx[cm * K_ + t] = j;
    dout[(size_t)BM * OUT_ + (size_t)cm * K_ + t] = (float)j;
  }
}

// ---------------------------------------------------------------------------
// Pre-kernel: W1/W2/Wm -> bf16 col-major
// ---------------------------------------------------------------------------
__global__ __launch_bounds__(TPB) void convert_weights_kernel(
    const float* __restrict__ W1, const float* __restrict__ W2,
    const float* __restrict__ Wm,
    unsigned short* __restrict__ Wt1, unsigned short* __restrict__ Wt2,
    unsigned short* __restrict__ Wtm)
{
  int t = blockIdx.x * TPB + threadIdx.x;
  if (t < 128 * 256) {
    int col = t >> 8, k = t & 255;
    Wt1[t] = bfu(W1[k * 128 + col]);
  } else if (t < 128 * 256 + 128 * 128) {
    int u = t - 128 * 256;
    int col = u >> 7, k = u & 127;
    Wt2[u] = bfu(W2[k * 128 + col]);
  } else {
    int w = t - (128 * 256 + 128 * 128);
    int col = w >> 7, k = w & 127;
    Wtm[w] = bfu(Wm[k * 256 + col]);
  }
}

// ---------------------------------------------------------------------------
// Kernel C: 2 centers/block — B-frag reuse across centers  [r33, unchanged]
// ---------------------------------------------------------------------------
__global__ __launch_bounds__(TPB, 3) void fuse_mlp_kernel(
    const float* __restrict__ feats, const int* __restrict__ cidx,
    const int* __restrict__ kidx,
    const float* __restrict__ ln1w, const float* __restrict__ ln1b,
    const unsigned short* __restrict__ Wt1, const float* __restrict__ b1,
    const unsigned short* __restrict__ Wt2, const float* __restrict__ b2,
    const unsigned short* __restrict__ Wtm, const float* __restrict__ bm,
    const float* __restrict__ ln2w, const float* __restrict__ ln2b,
    const float* __restrict__ res_scale,
    float* __restrict__ dout)
{
  const int cm0 = blockIdx.x * 2;
  const int b   = cm0 >> 12;
  const int tid = threadIdx.x;
  const int lane = tid & 63, wv = tid >> 6;

  __shared__ float cf[2][C_];
  __shared__ __align__(16) unsigned short nb[2][K_][136];
  __shared__ __align__(16) unsigned short cn[2][K_][264];
  __shared__ __align__(16) unsigned short hb[2][K_][136];
  __shared__ __align__(16) unsigned short wbb[2][K_][136];
  __shared__ __align__(16) unsigned short fvb[2][136];
  __shared__ float outb[2][OUT_];
  __shared__ float red[4];
  __shared__ int nidx[2][K_];

  if (tid < 32) {
    int c = tid >> 4, t = tid & 15;
    nidx[c][t] = kidx[(cm0 + c) * K_ + t];
  }
  __syncthreads();

  {
    for (int t = tid; t < 1088; t += TPB) {
      int c = (t >= 544) ? 1 : 0;
      int u = t - c * 544;
      int row = u >> 5, c4 = u & 31;
      int src = (row == 0) ? cidx[cm0 + c] : nidx[c][row - 1];
      float4 val = *(const float4*)&feats[((size_t)b * N_ + src) * C_ + c4 * 4];
      if (row == 0) {
        *(float4*)&cf[c][c4 * 4] = val;
      } else {
        int r = row - 1, cc = c4 * 4;
        nb[c][r][cc]     = bfu(val.x);
        nb[c][r][cc + 1] = bfu(val.y);
        nb[c][r][cc + 2] = bfu(val.z);
        nb[c][r][cc + 3] = bfu(val.w);
      }
    }
  }
  __syncthreads();

  for (int kk = 0; kk < 4; kk++) {
    int k = wv * 4 + kk;
#pragma unroll
    for (int c = 0; c < 2; c++) {
      float x0 = cf[c][lane];
      float x1 = cf[c][lane + 64];
      float x2 = b2f(nb[c][k][lane]);
      float x3 = b2f(nb[c][k][lane + 64]);
      float ssum = ((x0 + x1) + (x2 + x3));
#pragma unroll
      for (int off = 1; off < 64; off <<= 1) ssum += __shfl_xor(ssum, off, 64);
      float mu = ssum * (1.0f / 256.0f);
      float d0 = x0 - mu, d1 = x1 - mu, d2 = x2 - mu, d3 = x3 - mu;
      float vs = fmaf(d0, d0, fmaf(d1, d1, fmaf(d2, d2, d3 * d3)));
#pragma unroll
      for (int off = 1; off < 64; off <<= 1) vs += __shfl_xor(vs, off, 64);
      float var = vs * (1.0f / 256.0f);
      float rs = 1.0f / __fsqrt_rn(var + LN_EPS_F);
      cn[c][k][lane]       = bfu(fmaf(d0 * rs, ln1w[lane],       ln1b[lane]));
      cn[c][k][lane + 64]  = bfu(fmaf(d1 * rs, ln1w[lane + 64],  ln1b[lane + 64]));
      cn[c][k][lane + 128] = bfu(fmaf(d2 * rs, ln1w[lane + 128], ln1b[lane + 128]));
      cn[c][k][lane + 192] = bfu(fmaf(d3 * rs, ln1w[lane + 192], ln1b[lane + 192]));
    }
  }
  __syncthreads();

  const int r16 = lane & 15;
  const int kg  = lane >> 4;
  const int c0 = (2 * wv) * 16 + r16;
  const int c1 = (2 * wv + 1) * 16 + r16;

  f32x4 a0[2] = {{0.f,0.f,0.f,0.f},{0.f,0.f,0.f,0.f}};
  f32x4 a1[2] = {{0.f,0.f,0.f,0.f},{0.f,0.f,0.f,0.f}};
#pragma unroll
  for (int kt = 0; kt < 8; kt++) {
    int k0 = kt * 32 + kg * 8;
    bf16x8 g0 = *(const bf16x8*)&Wt1[(size_t)c0 * 256 + k0];
    bf16x8 g1 = *(const bf16x8*)&Wt1[(size_t)c1 * 256 + k0];
#pragma unroll
    for (int c = 0; c < 2; c++) {
      bf16x8 af = *(const bf16x8*)&cn[c][r16][k0];
      a0[c] = __builtin_amdgcn_mfma_f32_16x16x32_bf16(af, g0, a0[c], 0, 0, 0);
      a1[c] = __builtin_amdgcn_mfma_f32_16x16x32_bf16(af, g1, a1[c], 0, 0, 0);
    }
  }
#pragma unroll
  for (int c = 0; c < 2; c++)
#pragma unroll
    for (int r = 0; r < 4; r++) {
      int ro = kg * 4 + r;
      hb[c][ro][c0] = bfu(fmaxf(a0[c][r] + b1[c0], 0.f));
      hb[c][ro][c1] = bfu(fmaxf(a1[c][r] + b1[c1], 0.f));
    }
  __syncthreads();

  f32x4 s0[2] = {{0.f,0.f,0.f,0.f},{0.f,0.f,0.f,0.f}};
  f32x4 s1[2] = {{0.f,0.f,0.f,0.f},{0.f,0.f,0.f,0.f}};
#pragma unroll
  for (int kt = 0; kt < 4; kt++) {
    int k0 = kt * 32 + kg * 8;
    bf16x8 g0 = *(const bf16x8*)&Wt2[(size_t)c0 * 128 + k0];
    bf16x8 g1 = *(const bf16x8*)&Wt2[(size_t)c1 * 128 + k0];
#pragma unroll
    for (int c = 0; c < 2; c++) {
      bf16x8 af = *(const bf16x8*)&hb[c][r16][k0];
      s0[c] = __builtin_amdgcn_mfma_f32_16x16x32_bf16(af, g0, s0[c], 0, 0, 0);
      s1[c] = __builtin_amdgcn_mfma_f32_16x16x32_bf16(af, g1, s1[c], 0, 0, 0);
    }
  }
#pragma unroll
  for (int c = 0; c < 2; c++)
#pragma unroll
    for (int r = 0; r < 4; r++) {
      int ro = kg * 4 + r;
      wbb[c][ro][c0] = bfu(1.0f / (1.0f + expf(-(s0[c][r] + b2[c0]))));
      wbb[c][ro][c1] = bfu(1.0f / (1.0f + expf(-(s1[c][r] + b2[c1]))));
    }
  __syncthreads();

  {
    int c = tid >> 7, col = tid & 127;
    float ssum = 0.f;
#pragma unroll
    for (int kq = 0; kq < 16; kq++)
      ssum = fmaf(b2f(nb[c][kq][col]), b2f(wbb[c][kq][col]), ssum);
    float wmean = ssum * (1.0f / 16.0f);
    fvb[c][col] = bfu(fmaf(res_scale[0], wmean, cf[c][col]));
  }
  __syncthreads();

#pragma unroll
  for (int i = 0; i < 4; i++) {
    int cb = (wv * 4 + i) * 16;
    f32x4 acc[2] = {{0.f,0.f,0.f,0.f},{0.f,0.f,0.f,0.f}};
#pragma unroll
    for (int kt = 0; kt < 4; kt++) {
      int k0 = kt * 32 + kg * 8;
      bf16x8 gf = *(const bf16x8*)&Wtm[(size_t)(cb + r16) * 128 + k0];
#pragma unroll
      for (int c = 0; c < 2; c++) {
        bf16x8 af = *(const bf16x8*)&fvb[c][k0];
        acc[c] = __builtin_amdgcn_mfma_f32_16x16x32_bf16(af, gf, acc[c], 0, 0, 0);
      }
    }
    if (kg == 0) {
      int cc = cb + r16;
#pragma unroll
      for (int c = 0; c < 2; c++)
        outb[c][cc] = fmaxf(acc[c][0] + bm[cc], 0.f);
    }
  }
  __syncthreads();

  for (int c = 0; c < 2; c++) {
    float outx = outb[c][tid];
    float s = outx;
#pragma unroll
    for (int off = 1; off < 64; off <<= 1) s += __shfl_xor(s, off, 64);
    if (lane == 0) red[wv] = s;
    __syncthreads();
    float mu = (red[0] + red[1] + red[2] + red[3]) * (1.0f / 256.0f);
    float d = outx - mu;
    float s2 = d * d;
#pragma unroll
    for (int off = 1; off < 64; off <<= 1) s2 += __shfl_xor(s2, off, 64);
    __syncthreads();
    if (lane == 0) red[wv] = s2;
    __syncthreads();
    float var = (red[0] + red[1] + red[2] + red[3]) * (1.0f / 256.0f);
    float rs2 = 1.0f / __fsqrt_rn(var + LN_EPS_F);
    dout[(size_t)(cm0 + c) * OUT_ + tid] = fmaf(d * rs2, ln2w[tid], ln2b[tid]);
    __syncthreads();
  }
}

// ---------------------------------------------------------------------------
extern "C" void kernel_launch(void* const* d_in, const int* in_sizes, int n_in,
                              void* d_out, int out_size, void* d_ws, size_t ws_size,
                              hipStream_t stream) {
  const float* points = (const float*)d_in[0];
  const float* feats  = (const float*)d_in[1];
  const int*   cidx   = (const int*)  d_in[2];
  const float* ln1w   = (const float*)d_in[3];
  const float* ln1b   = (const float*)d_in[4];
  const float* W1     = (const float*)d_in[5];
  const float* b1     = (const float*)d_in[6];
  const float* W2     = (const float*)d_in[7];
  const float* b2     = (const float*)d_in[8];
  const float* Wm     = (const float*)d_in[9];
  const float* bm     = (const float*)d_in[10];
  const float* ln2w   = (const float*)d_in[11];
  const float* ln2b   = (const float*)d_in[12];
  const float* rscale = (const float*)d_in[13];

  float* out = (float*)d_out;
  char*  ws  = (char*)d_ws;
  float* pvals = (float*)ws;
  int*   pidx  = (int*)(ws + 16777216);
  int*   kidx  = (int*)(ws + 33554432);
  unsigned short* Wt1 = (unsigned short*)(ws + 34603008);
  unsigned short* Wt2 = (unsigned short*)(ws + 34603008 + 65536);
  unsigned short* Wtm = (unsigned short*)(ws + 34603008 + 65536 + 32768);

  convert_weights_kernel<<<(128 * 256 + 128 * 128 + 256 * 128 + TPB - 1) / TPB,
                           TPB, 0, stream>>>(W1, W2, Wm, Wt1, Wt2, Wtm);
  knn_partial_kernel<<<dim3(S_CHUNKS, M_ / TPB, B_), TPB, 0, stream>>>(points, cidx, pvals, pidx);
  knn_merge_kernel<<<BM / 64, 64, 0, stream>>>(pvals, pidx, kidx, out);
  fuse_mlp_kernel<<<BM / 2, TPB, 0, stream>>>(feats, cidx, kidx,
                                              ln1w, ln1b, Wt1, b1, Wt2, b2, Wtm, bm,
                                              ln2w, ln2b, rscale, out);
}

// Round 35
// 470.198 us; speedup vs baseline: 1.1402x; 1.1402x over previous
//
#include <hip/hip_runtime.h>
#include <hip/hip_bf16.h>
#include <math.h>

#define B_ 4
#define N_ 16384
#define M_ 4096
#define K_ 16
#define C_ 128
#define OUT_ 256
#define S_CHUNKS 16
#define CHUNK 1024
#define TPB 256
#define MAX_R 0.3f
#define BIGF 1e9f
#define LN_EPS_F 1e-5f
#define SEPS 1e-6f
#define BM (B_ * M_)

// KNN exactness (r25, FROZEN): d2 = fma(-2,dot,aq+bq), sq=(x²+z²)+y²,
// dot=fma(c2p2,fma(c1p1,c0p0)), dist=sqrt(d2+eps)<=0.3, (dist,idx) stable.
// r34 lesson: lane-level pretest is useless — wave executes the union
// (P(any-lane passes) ~ 1). r35: buffer RAW d2; sqrt/mask/gate move to the
// DRAIN (exact frozen path, append order = index order => identical ties).
// Hot loop: read, dot, d2, cmp, masked-append, __any. ~28 insts/iter.

typedef __attribute__((ext_vector_type(8))) short bf16x8;
typedef __attribute__((ext_vector_type(4))) float f32x4;

__device__ __forceinline__ unsigned short bfu(float f) {
  __hip_bfloat16 h = __float2bfloat16(f);
  return *reinterpret_cast<unsigned short*>(&h);
}
__device__ __forceinline__ float b2f(unsigned short u) {
  unsigned x = ((unsigned)u) << 16;
  return __uint_as_float(x);
}

// ---------------------------------------------------------------------------
// Kernel A: per-(center, chunk) partial top-16, d2-deferred buffer
// ---------------------------------------------------------------------------
__global__ __launch_bounds__(TPB) void knn_partial_kernel(
    const float* __restrict__ points, const int* __restrict__ cidx,
    float* __restrict__ pvals, int* __restrict__ pidx)
{
#pragma clang fp contract(off)
  const int s  = blockIdx.x;
  const int mg = blockIdx.y;
  const int b  = blockIdx.z;
  const int tid = threadIdx.x;

  __shared__ float4 pts[CHUNK];
  __shared__ unsigned long long buf[8][TPB];

  const int j0 = s * CHUNK;
  for (int e = tid; e < CHUNK; e += TPB) {
    int j = j0 + e;
    float x = points[(b * N_ + j) * 3 + 0];
    float y = points[(b * N_ + j) * 3 + 1];
    float z = points[(b * N_ + j) * 3 + 2];
    float bq = (x * x + z * z) + y * y;      // einsum SSE2 tree
    pts[e] = make_float4(x, y, z, bq);
  }

  const int m  = mg * TPB + tid;
  const int cm = b * M_ + m;
  const int ci = cidx[cm];
  const float cx = points[(b * N_ + ci) * 3 + 0];
  const float cy = points[(b * N_ + ci) * 3 + 1];
  const float cz = points[(b * N_ + ci) * 3 + 2];
  const float aq = (cx * cx + cz * cz) + cy * cy;   // einsum SSE2 tree
  __syncthreads();

  float v[16];
  int   id[16];
#pragma unroll
  for (int t = 0; t < 16; t++) { v[t] = 3.4e38f; id[t] = 0; }
  float v15q = 0.0905f;   // conservative d2 gate (covers dist<=0.3 mask)
  int cnt = 0;

  for (int e = 0; e < CHUNK; e++) {
    float4 p = pts[e];
    float dot = fmaf(cz, p.z, fmaf(cy, p.y, cx * p.x));  // BLAS fma chain
    float d2 = fmaf(-2.0f, dot, aq + p.w);
    if (d2 < v15q) {
      buf[cnt][tid] =
          ((unsigned long long)__float_as_uint(d2) << 32) | (unsigned)(j0 + e);
      cnt++;
    }
    if (__any(cnt == 8)) {
      // drain: EXACT frozen path per buffered entry, append order = idx order
      for (int ss = 0; ss < 8; ss++) {
        if (ss < cnt) {
          unsigned long long kk = buf[ss][tid];
          float d2v = __uint_as_float((unsigned)(kk >> 32));
          int j = (int)(kk & 0xffffffffULL);
          float d2c = fmaxf(d2v, 0.0f);
          float dist = __fsqrt_rn(d2c + SEPS);
          float md = (dist <= MAX_R) ? dist : BIGF;
          if (md < v[15]) {
            bool cg[16];
#pragma unroll
            for (int t = 0; t < 16; t++) cg[t] = (v[t] > md);
#pragma unroll
            for (int t = 15; t >= 1; t--) {
              v[t]  = cg[t - 1] ? v[t - 1]  : (cg[t] ? md : v[t]);
              id[t] = cg[t - 1] ? id[t - 1] : (cg[t] ? j  : id[t]);
            }
            if (cg[0]) { v[0] = md; id[0] = j; }
          }
        }
      }
      cnt = 0;
      float v15 = v[15];
      v15q = fminf(0.0905f, fmaf(v15, v15, 1e-6f));
    }
  }

  // final drain
  for (int ss = 0; ss < 8; ss++) {
    if (ss < cnt) {
      unsigned long long kk = buf[ss][tid];
      float d2v = __uint_as_float((unsigned)(kk >> 32));
      int j = (int)(kk & 0xffffffffULL);
      float d2c = fmaxf(d2v, 0.0f);
      float dist = __fsqrt_rn(d2c + SEPS);
      float md = (dist <= MAX_R) ? dist : BIGF;
      if (md < v[15]) {
        bool cg[16];
#pragma unroll
        for (int t = 0; t < 16; t++) cg[t] = (v[t] > md);
#pragma unroll
        for (int t = 15; t >= 1; t--) {
          v[t]  = cg[t - 1] ? v[t - 1]  : (cg[t] ? md : v[t]);
          id[t] = cg[t - 1] ? id[t - 1] : (cg[t] ? j  : id[t]);
        }
        if (cg[0]) { v[0] = md; id[0] = j; }
      }
    }
  }

#pragma unroll
  for (int t = 0; t < 16; t++) {
    int o = (s * 16 + t) * BM + cm;
    pvals[o] = v[t];
    pidx[o]  = id[t];
  }
}

// ---------------------------------------------------------------------------
// Kernel B: merge S_CHUNKS sorted partial lists (64 thr/block, 256 blocks)
// ---------------------------------------------------------------------------
__global__ __launch_bounds__(64) void knn_merge_kernel(
    const float* __restrict__ pvals, const int* __restrict__ pidx,
    int* __restrict__ kidx, float* __restrict__ dout)
{
  const int cm = blockIdx.x * 64 + threadIdx.x;

  unsigned long long key[16];
#pragma unroll
  for (int t = 0; t < 16; t++) {
    int o = t * BM + cm;
    unsigned int vb = __float_as_uint(pvals[o]);
    key[t] = ((unsigned long long)vb << 32) | (unsigned int)pidx[o];
  }
  for (int s = 1; s < S_CHUNKS; s++) {
    for (int t2 = 0; t2 < 16; t2++) {
      int o = (s * 16 + t2) * BM + cm;
      unsigned int vb = __float_as_uint(pvals[o]);
      unsigned long long Kk = ((unsigned long long)vb << 32) | (unsigned int)pidx[o];
      if (Kk >= key[15]) break;
      bool cg[16];
#pragma unroll
      for (int t = 0; t < 16; t++) cg[t] = (key[t] > Kk);
#pragma unroll
      for (int t = 15; t >= 1; t--)
        key[t] = cg[t - 1] ? key[t - 1] : (cg[t] ? Kk : key[t]);
      if (cg[0]) key[0] = Kk;
    }
  }
#pragma unroll
  for (int t = 0; t < 16; t++) {
    int j = (int)(key[t] & 0xffffffffULL);
    kidx[cm * K_ + t] = j;
    dout[(size_t)BM * OUT_ + (size_t)cm * K_ + t] = (float)j;
  }
}

// ---------------------------------------------------------------------------
// Pre-kernel: W1/W2/Wm -> bf16 col-major
// ---------------------------------------------------------------------------
__global__ __launch_bounds__(TPB) void convert_weights_kernel(
    const float* __restrict__ W1, const float* __restrict__ W2,
    const float* __restrict__ Wm,
    unsigned short* __restrict__ Wt1, unsigned short* __restrict__ Wt2,
    unsigned short* __restrict__ Wtm)
{
  int t = blockIdx.x * TPB + threadIdx.x;
  if (t < 128 * 256) {
    int col = t >> 8, k = t & 255;
    Wt1[t] = bfu(W1[k * 128 + col]);
  } else if (t < 128 * 256 + 128 * 128) {
    int u = t - 128 * 256;
    int col = u >> 7, k = u & 127;
    Wt2[u] = bfu(W2[k * 128 + col]);
  } else {
    int w = t - (128 * 256 + 128 * 128);
    int col = w >> 7, k = w & 127;
    Wtm[w] = bfu(Wm[k * 256 + col]);
  }
}

// ---------------------------------------------------------------------------
// Kernel C: 2 centers/block — B-frag reuse across centers  [r33, unchanged]
// ---------------------------------------------------------------------------
__global__ __launch_bounds__(TPB, 3) void fuse_mlp_kernel(
    const float* __restrict__ feats, const int* __restrict__ cidx,
    const int* __restrict__ kidx,
    const float* __restrict__ ln1w, const float* __restrict__ ln1b,
    const unsigned short* __restrict__ Wt1, const float* __restrict__ b1,
    const unsigned short* __restrict__ Wt2, const float* __restrict__ b2,
    const unsigned short* __restrict__ Wtm, const float* __restrict__ bm,
    const float* __restrict__ ln2w, const float* __restrict__ ln2b,
    const float* __restrict__ res_scale,
    float* __restrict__ dout)
{
  const int cm0 = blockIdx.x * 2;
  const int b   = cm0 >> 12;
  const int tid = threadIdx.x;
  const int lane = tid & 63, wv = tid >> 6;

  __shared__ float cf[2][C_];
  __shared__ __align__(16) unsigned short nb[2][K_][136];
  __shared__ __align__(16) unsigned short cn[2][K_][264];
  __shared__ __align__(16) unsigned short hb[2][K_][136];
  __shared__ __align__(16) unsigned short wbb[2][K_][136];
  __shared__ __align__(16) unsigned short fvb[2][136];
  __shared__ float outb[2][OUT_];
  __shared__ float red[4];
  __shared__ int nidx[2][K_];

  if (tid < 32) {
    int c = tid >> 4, t = tid & 15;
    nidx[c][t] = kidx[(cm0 + c) * K_ + t];
  }
  __syncthreads();

  {
    for (int t = tid; t < 1088; t += TPB) {
      int c = (t >= 544) ? 1 : 0;
      int u = t - c * 544;
      int row = u >> 5, c4 = u & 31;
      int src = (row == 0) ? cidx[cm0 + c] : nidx[c][row - 1];
      float4 val = *(const float4*)&feats[((size_t)b * N_ + src) * C_ + c4 * 4];
      if (row == 0) {
        *(float4*)&cf[c][c4 * 4] = val;
      } else {
        int r = row - 1, cc = c4 * 4;
        nb[c][r][cc]     = bfu(val.x);
        nb[c][r][cc + 1] = bfu(val.y);
        nb[c][r][cc + 2] = bfu(val.z);
        nb[c][r][cc + 3] = bfu(val.w);
      }
    }
  }
  __syncthreads();

  for (int kk = 0; kk < 4; kk++) {
    int k = wv * 4 + kk;
#pragma unroll
    for (int c = 0; c < 2; c++) {
      float x0 = cf[c][lane];
      float x1 = cf[c][lane + 64];
      float x2 = b2f(nb[c][k][lane]);
      float x3 = b2f(nb[c][k][lane + 64]);
      float ssum = ((x0 + x1) + (x2 + x3));
#pragma unroll
      for (int off = 1; off < 64; off <<= 1) ssum += __shfl_xor(ssum, off, 64);
      float mu = ssum * (1.0f / 256.0f);
      float d0 = x0 - mu, d1 = x1 - mu, d2 = x2 - mu, d3 = x3 - mu;
      float vs = fmaf(d0, d0, fmaf(d1, d1, fmaf(d2, d2, d3 * d3)));
#pragma unroll
      for (int off = 1; off < 64; off <<= 1) vs += __shfl_xor(vs, off, 64);
      float var = vs * (1.0f / 256.0f);
      float rs = 1.0f / __fsqrt_rn(var + LN_EPS_F);
      cn[c][k][lane]       = bfu(fmaf(d0 * rs, ln1w[lane],       ln1b[lane]));
      cn[c][k][lane + 64]  = bfu(fmaf(d1 * rs, ln1w[lane + 64],  ln1b[lane + 64]));
      cn[c][k][lane + 128] = bfu(fmaf(d2 * rs, ln1w[lane + 128], ln1b[lane + 128]));
      cn[c][k][lane + 192] = bfu(fmaf(d3 * rs, ln1w[lane + 192], ln1b[lane + 192]));
    }
  }
  __syncthreads();

  const int r16 = lane & 15;
  const int kg  = lane >> 4;
  const int c0 = (2 * wv) * 16 + r16;
  const int c1 = (2 * wv + 1) * 16 + r16;

  f32x4 a0[2] = {{0.f,0.f,0.f,0.f},{0.f,0.f,0.f,0.f}};
  f32x4 a1[2] = {{0.f,0.f,0.f,0.f},{0.f,0.f,0.f,0.f}};
#pragma unroll
  for (int kt = 0; kt < 8; kt++) {
    int k0 = kt * 32 + kg * 8;
    bf16x8 g0 = *(const bf16x8*)&Wt1[(size_t)c0 * 256 + k0];
    bf16x8 g1 = *(const bf16x8*)&Wt1[(size_t)c1 * 256 + k0];
#pragma unroll
    for (int c = 0; c < 2; c++) {
      bf16x8 af = *(const bf16x8*)&cn[c][r16][k0];
      a0[c] = __builtin_amdgcn_mfma_f32_16x16x32_bf16(af, g0, a0[c], 0, 0, 0);
      a1[c] = __builtin_amdgcn_mfma_f32_16x16x32_bf16(af, g1, a1[c], 0, 0, 0);
    }
  }
#pragma unroll
  for (int c = 0; c < 2; c++)
#pragma unroll
    for (int r = 0; r < 4; r++) {
      int ro = kg * 4 + r;
      hb[c][ro][c0] = bfu(fmaxf(a0[c][r] + b1[c0], 0.f));
      hb[c][ro][c1] = bfu(fmaxf(a1[c][r] + b1[c1], 0.f));
    }
  __syncthreads();

  f32x4 s0[2] = {{0.f,0.f,0.f,0.f},{0.f,0.f,0.f,0.f}};
  f32x4 s1[2] = {{0.f,0.f,0.f,0.f},{0.f,0.f,0.f,0.f}};
#pragma unroll
  for (int kt = 0; kt < 4; kt++) {
    int k0 = kt * 32 + kg * 8;
    bf16x8 g0 = *(const bf16x8*)&Wt2[(size_t)c0 * 128 + k0];
    bf16x8 g1 = *(const bf16x8*)&Wt2[(size_t)c1 * 128 + k0];
#pragma unroll
    for (int c = 0; c < 2; c++) {
      bf16x8 af = *(const bf16x8*)&hb[c][r16][k0];
      s0[c] = __builtin_amdgcn_mfma_f32_16x16x32_bf16(af, g0, s0[c], 0, 0, 0);
      s1[c] = __builtin_amdgcn_mfma_f32_16x16x32_bf16(af, g1, s1[c], 0, 0, 0);
    }
  }
#pragma unroll
  for (int c = 0; c < 2; c++)
#pragma unroll
    for (int r = 0; r < 4; r++) {
      int ro = kg * 4 + r;
      wbb[c][ro][c0] = bfu(1.0f / (1.0f + expf(-(s0[c][r] + b2[c0]))));
      wbb[c][ro][c1] = bfu(1.0f / (1.0f + expf(-(s1[c][r] + b2[c1]))));
    }
  __syncthreads();

  {
    int c = tid >> 7, col = tid & 127;
    float ssum = 0.f;
#pragma unroll
    for (int kq = 0; kq < 16; kq++)
      ssum = fmaf(b2f(nb[c][kq][col]), b2f(wbb[c][kq][col]), ssum);
    float wmean = ssum * (1.0f / 16.0f);
    fvb[c][col] = bfu(fmaf(res_scale[0], wmean, cf[c][col]));
  }
  __syncthreads();

#pragma unroll
  for (int i = 0; i < 4; i++) {
    int cb = (wv * 4 + i) * 16;
    f32x4 acc[2] = {{0.f,0.f,0.f,0.f},{0.f,0.f,0.f,0.f}};
#pragma unroll
    for (int kt = 0; kt < 4; kt++) {
      int k0 = kt * 32 + kg * 8;
      bf16x8 gf = *(const bf16x8*)&Wtm[(size_t)(cb + r16) * 128 + k0];
#pragma unroll
      for (int c = 0; c < 2; c++) {
        bf16x8 af = *(const bf16x8*)&fvb[c][k0];
        acc[c] = __builtin_amdgcn_mfma_f32_16x16x32_bf16(af, gf, acc[c], 0, 0, 0);
      }
    }
    if (kg == 0) {
      int cc = cb + r16;
#pragma unroll
      for (int c = 0; c < 2; c++)
        outb[c][cc] = fmaxf(acc[c][0] + bm[cc], 0.f);
    }
  }
  __syncthreads();

  for (int c = 0; c < 2; c++) {
    float outx = outb[c][tid];
    float s = outx;
#pragma unroll
    for (int off = 1; off < 64; off <<= 1) s += __shfl_xor(s, off, 64);
    if (lane == 0) red[wv] = s;
    __syncthreads();
    float mu = (red[0] + red[1] + red[2] + red[3]) * (1.0f / 256.0f);
    float d = outx - mu;
    float s2 = d * d;
#pragma unroll
    for (int off = 1; off < 64; off <<= 1) s2 += __shfl_xor(s2, off, 64);
    __syncthreads();
    if (lane == 0) red[wv] = s2;
    __syncthreads();
    float var = (red[0] + red[1] + red[2] + red[3]) * (1.0f / 256.0f);
    float rs2 = 1.0f / __fsqrt_rn(var + LN_EPS_F);
    dout[(size_t)(cm0 + c) * OUT_ + tid] = fmaf(d * rs2, ln2w[tid], ln2b[tid]);
    __syncthreads();
  }
}

// ---------------------------------------------------------------------------
extern "C" void kernel_launch(void* const* d_in, const int* in_sizes, int n_in,
                              void* d_out, int out_size, void* d_ws, size_t ws_size,
                              hipStream_t stream) {
  const float* points = (const float*)d_in[0];
  const float* feats  = (const float*)d_in[1];
  const int*   cidx   = (const int*)  d_in[2];
  const float* ln1w   = (const float*)d_in[3];
  const float* ln1b   = (const float*)d_in[4];
  const float* W1     = (const float*)d_in[5];
  const float* b1     = (const float*)d_in[6];
  const float* W2     = (const float*)d_in[7];
  const float* b2     = (const float*)d_in[8];
  const float* Wm     = (const float*)d_in[9];
  const float* bm     = (const float*)d_in[10];
  const float* ln2w   = (const float*)d_in[11];
  const float* ln2b   = (const float*)d_in[12];
  const float* rscale = (const float*)d_in[13];

  float* out = (float*)d_out;
  char*  ws  = (char*)d_ws;
  float* pvals = (float*)ws;
  int*   pidx  = (int*)(ws + 16777216);
  int*   kidx  = (int*)(ws + 33554432);
  unsigned short* Wt1 = (unsigned short*)(ws + 34603008);
  unsigned short* Wt2 = (unsigned short*)(ws + 34603008 + 65536);
  unsigned short* Wtm = (unsigned short*)(ws + 34603008 + 65536 + 32768);

  convert_weights_kernel<<<(128 * 256 + 128 * 128 + 256 * 128 + TPB - 1) / TPB,
                           TPB, 0, stream>>>(W1, W2, Wm, Wt1, Wt2, Wtm);
  knn_partial_kernel<<<dim3(S_CHUNKS, M_ / TPB, B_), TPB, 0, stream>>>(points, cidx, pvals, pidx);
  knn_merge_kernel<<<BM / 64, 64, 0, stream>>>(pvals, pidx, kidx, out);
  fuse_mlp_kernel<<<BM / 2, TPB, 0, stream>>>(feats, cidx, kidx,
                                              ln1w, ln1b, Wt1, b1, Wt2, b2, Wtm, bm,
                                              ln2w, ln2b, rscale, out);
}

// Round 36
// 443.320 us; speedup vs baseline: 1.2094x; 1.0606x over previous
//
#include <hip/hip_runtime.h>
#include <hip/hip_bf16.h>
#include <math.h>

#define B_ 4
#define N_ 16384
#define M_ 4096
#define K_ 16
#define C_ 128
#define OUT_ 256
#define S_CHUNKS 16
#define CHUNK 1024
#define TPB 256
#define MAX_R 0.3f
#define BIGF 1e9f
#define LN_EPS_F 1e-5f
#define SEPS 1e-6f
#define BM (B_ * M_)

// KNN exactness (r25, FROZEN): d2 = fma(-2,dot,aq+bq), sq=(x²+z²)+y²,
// dot=fma(c2p2,fma(c1p1,c0p0)), dist=sqrt(d2+eps)<=0.3, (dist,idx) stable.
// r35: A d2-deferred (~200us), C leads at 237us (occ 33%, LDS 47KB = 3
// blocks/CU). r36: LDS ALIAS — cn (dead after GEMM1 reg-reads) shares a pool
// with hb+wbb; extra barrier between GEMM1 reads and hb writes. 30KB ->
// 5 blocks/CU.

typedef __attribute__((ext_vector_type(8))) short bf16x8;
typedef __attribute__((ext_vector_type(4))) float f32x4;

__device__ __forceinline__ unsigned short bfu(float f) {
  __hip_bfloat16 h = __float2bfloat16(f);
  return *reinterpret_cast<unsigned short*>(&h);
}
__device__ __forceinline__ float b2f(unsigned short u) {
  unsigned x = ((unsigned)u) << 16;
  return __uint_as_float(x);
}

// ---------------------------------------------------------------------------
// Kernel A: per-(center, chunk) partial top-16, d2-deferred buffer  [r35]
// ---------------------------------------------------------------------------
__global__ __launch_bounds__(TPB) void knn_partial_kernel(
    const float* __restrict__ points, const int* __restrict__ cidx,
    float* __restrict__ pvals, int* __restrict__ pidx)
{
#pragma clang fp contract(off)
  const int s  = blockIdx.x;
  const int mg = blockIdx.y;
  const int b  = blockIdx.z;
  const int tid = threadIdx.x;

  __shared__ float4 pts[CHUNK];
  __shared__ unsigned long long buf[8][TPB];

  const int j0 = s * CHUNK;
  for (int e = tid; e < CHUNK; e += TPB) {
    int j = j0 + e;
    float x = points[(b * N_ + j) * 3 + 0];
    float y = points[(b * N_ + j) * 3 + 1];
    float z = points[(b * N_ + j) * 3 + 2];
    float bq = (x * x + z * z) + y * y;      // einsum SSE2 tree
    pts[e] = make_float4(x, y, z, bq);
  }

  const int m  = mg * TPB + tid;
  const int cm = b * M_ + m;
  const int ci = cidx[cm];
  const float cx = points[(b * N_ + ci) * 3 + 0];
  const float cy = points[(b * N_ + ci) * 3 + 1];
  const float cz = points[(b * N_ + ci) * 3 + 2];
  const float aq = (cx * cx + cz * cz) + cy * cy;   // einsum SSE2 tree
  __syncthreads();

  float v[16];
  int   id[16];
#pragma unroll
  for (int t = 0; t < 16; t++) { v[t] = 3.4e38f; id[t] = 0; }
  float v15q = 0.0905f;
  int cnt = 0;

  for (int e = 0; e < CHUNK; e++) {
    float4 p = pts[e];
    float dot = fmaf(cz, p.z, fmaf(cy, p.y, cx * p.x));  // BLAS fma chain
    float d2 = fmaf(-2.0f, dot, aq + p.w);
    if (d2 < v15q) {
      buf[cnt][tid] =
          ((unsigned long long)__float_as_uint(d2) << 32) | (unsigned)(j0 + e);
      cnt++;
    }
    if (__any(cnt == 8)) {
      for (int ss = 0; ss < 8; ss++) {
        if (ss < cnt) {
          unsigned long long kk = buf[ss][tid];
          float d2v = __uint_as_float((unsigned)(kk >> 32));
          int j = (int)(kk & 0xffffffffULL);
          float d2c = fmaxf(d2v, 0.0f);
          float dist = __fsqrt_rn(d2c + SEPS);
          float md = (dist <= MAX_R) ? dist : BIGF;
          if (md < v[15]) {
            bool cg[16];
#pragma unroll
            for (int t = 0; t < 16; t++) cg[t] = (v[t] > md);
#pragma unroll
            for (int t = 15; t >= 1; t--) {
              v[t]  = cg[t - 1] ? v[t - 1]  : (cg[t] ? md : v[t]);
              id[t] = cg[t - 1] ? id[t - 1] : (cg[t] ? j  : id[t]);
            }
            if (cg[0]) { v[0] = md; id[0] = j; }
          }
        }
      }
      cnt = 0;
      float v15 = v[15];
      v15q = fminf(0.0905f, fmaf(v15, v15, 1e-6f));
    }
  }

  for (int ss = 0; ss < 8; ss++) {
    if (ss < cnt) {
      unsigned long long kk = buf[ss][tid];
      float d2v = __uint_as_float((unsigned)(kk >> 32));
      int j = (int)(kk & 0xffffffffULL);
      float d2c = fmaxf(d2v, 0.0f);
      float dist = __fsqrt_rn(d2c + SEPS);
      float md = (dist <= MAX_R) ? dist : BIGF;
      if (md < v[15]) {
        bool cg[16];
#pragma unroll
        for (int t = 0; t < 16; t++) cg[t] = (v[t] > md);
#pragma unroll
        for (int t = 15; t >= 1; t--) {
          v[t]  = cg[t - 1] ? v[t - 1]  : (cg[t] ? md : v[t]);
          id[t] = cg[t - 1] ? id[t - 1] : (cg[t] ? j  : id[t]);
        }
        if (cg[0]) { v[0] = md; id[0] = j; }
      }
    }
  }

#pragma unroll
  for (int t = 0; t < 16; t++) {
    int o = (s * 16 + t) * BM + cm;
    pvals[o] = v[t];
    pidx[o]  = id[t];
  }
}

// ---------------------------------------------------------------------------
// Kernel B: merge S_CHUNKS sorted partial lists (64 thr/block)
// ---------------------------------------------------------------------------
__global__ __launch_bounds__(64) void knn_merge_kernel(
    const float* __restrict__ pvals, const int* __restrict__ pidx,
    int* __restrict__ kidx, float* __restrict__ dout)
{
  const int cm = blockIdx.x * 64 + threadIdx.x;

  unsigned long long key[16];
#pragma unroll
  for (int t = 0; t < 16; t++) {
    int o = t * BM + cm;
    unsigned int vb = __float_as_uint(pvals[o]);
    key[t] = ((unsigned long long)vb << 32) | (unsigned int)pidx[o];
  }
  for (int s = 1; s < S_CHUNKS; s++) {
    for (int t2 = 0; t2 < 16; t2++) {
      int o = (s * 16 + t2) * BM + cm;
      unsigned int vb = __float_as_uint(pvals[o]);
      unsigned long long Kk = ((unsigned long long)vb << 32) | (unsigned int)pidx[o];
      if (Kk >= key[15]) break;
      bool cg[16];
#pragma unroll
      for (int t = 0; t < 16; t++) cg[t] = (key[t] > Kk);
#pragma unroll
      for (int t = 15; t >= 1; t--)
        key[t] = cg[t - 1] ? key[t - 1] : (cg[t] ? Kk : key[t]);
      if (cg[0]) key[0] = Kk;
    }
  }
#pragma unroll
  for (int t = 0; t < 16; t++) {
    int j = (int)(key[t] & 0xffffffffULL);
    kidx[cm * K_ + t] = j;
    dout[(size_t)BM * OUT_ + (size_t)cm * K_ + t] = (float)j;
  }
}

// ---------------------------------------------------------------------------
// Pre-kernel: W1/W2/Wm -> bf16 col-major
// ---------------------------------------------------------------------------
__global__ __launch_bounds__(TPB) void convert_weights_kernel(
    const float* __restrict__ W1, const float* __restrict__ W2,
    const float* __restrict__ Wm,
    unsigned short* __restrict__ Wt1, unsigned short* __restrict__ Wt2,
    unsigned short* __restrict__ Wtm)
{
  int t = blockIdx.x * TPB + threadIdx.x;
  if (t < 128 * 256) {
    int col = t >> 8, k = t & 255;
    Wt1[t] = bfu(W1[k * 128 + col]);
  } else if (t < 128 * 256 + 128 * 128) {
    int u = t - 128 * 256;
    int col = u >> 7, k = u & 127;
    Wt2[u] = bfu(W2[k * 128 + col]);
  } else {
    int w = t - (128 * 256 + 128 * 128);
    int col = w >> 7, k = w & 127;
    Wtm[w] = bfu(Wm[k * 256 + col]);
  }
}

// ---------------------------------------------------------------------------
// Kernel C: 2 centers/block, LDS-aliased cn <-> (hb|wbb), 5 blocks/CU
// ---------------------------------------------------------------------------
__global__ __launch_bounds__(TPB, 5) void fuse_mlp_kernel(
    const float* __restrict__ feats, const int* __restrict__ cidx,
    const int* __restrict__ kidx,
    const float* __restrict__ ln1w, const float* __restrict__ ln1b,
    const unsigned short* __restrict__ Wt1, const float* __restrict__ b1,
    const unsigned short* __restrict__ Wt2, const float* __restrict__ b2,
    const unsigned short* __restrict__ Wtm, const float* __restrict__ bm,
    const float* __restrict__ ln2w, const float* __restrict__ ln2b,
    const float* __restrict__ res_scale,
    float* __restrict__ dout)
{
  const int cm0 = blockIdx.x * 2;
  const int b   = cm0 >> 12;
  const int tid = threadIdx.x;
  const int lane = tid & 63, wv = tid >> 6;

  __shared__ float cf[2][C_];
  __shared__ __align__(16) unsigned short nb[2][K_][136];
  __shared__ __align__(16) char pool[2 * K_ * 272 * 2];   // cn | (hb,wbb)
  __shared__ __align__(16) unsigned short fvb[2][136];
  __shared__ float outb[2][OUT_];
  __shared__ float red[4];
  __shared__ int nidx[2][K_];

  typedef unsigned short cn_t[K_][272];
  typedef unsigned short hw_t[K_][136];
  cn_t* cn  = (cn_t*)pool;                         // [2][16][272] = 17408 B
  hw_t* hb  = (hw_t*)pool;                         // [2][16][136] =  8704 B
  hw_t* wbb = (hw_t*)(pool + 2 * K_ * 136 * 2);    // next 8704 B

  if (tid < 32) {
    int c = tid >> 4, t = tid & 15;
    nidx[c][t] = kidx[(cm0 + c) * K_ + t];
  }
  __syncthreads();

  {
    for (int t = tid; t < 1088; t += TPB) {
      int c = (t >= 544) ? 1 : 0;
      int u = t - c * 544;
      int row = u >> 5, c4 = u & 31;
      int src = (row == 0) ? cidx[cm0 + c] : nidx[c][row - 1];
      float4 val = *(const float4*)&feats[((size_t)b * N_ + src) * C_ + c4 * 4];
      if (row == 0) {
        *(float4*)&cf[c][c4 * 4] = val;
      } else {
        int r = row - 1, cc = c4 * 4;
        nb[c][r][cc]     = bfu(val.x);
        nb[c][r][cc + 1] = bfu(val.y);
        nb[c][r][cc + 2] = bfu(val.z);
        nb[c][r][cc + 3] = bfu(val.w);
      }
    }
  }
  __syncthreads();

  for (int kk = 0; kk < 4; kk++) {
    int k = wv * 4 + kk;
#pragma unroll
    for (int c = 0; c < 2; c++) {
      float x0 = cf[c][lane];
      float x1 = cf[c][lane + 64];
      float x2 = b2f(nb[c][k][lane]);
      float x3 = b2f(nb[c][k][lane + 64]);
      float ssum = ((x0 + x1) + (x2 + x3));
#pragma unroll
      for (int off = 1; off < 64; off <<= 1) ssum += __shfl_xor(ssum, off, 64);
      float mu = ssum * (1.0f / 256.0f);
      float d0 = x0 - mu, d1 = x1 - mu, d2 = x2 - mu, d3 = x3 - mu;
      float vs = fmaf(d0, d0, fmaf(d1, d1, fmaf(d2, d2, d3 * d3)));
#pragma unroll
      for (int off = 1; off < 64; off <<= 1) vs += __shfl_xor(vs, off, 64);
      float var = vs * (1.0f / 256.0f);
      float rs = 1.0f / __fsqrt_rn(var + LN_EPS_F);
      cn[c][k][lane]       = bfu(fmaf(d0 * rs, ln1w[lane],       ln1b[lane]));
      cn[c][k][lane + 64]  = bfu(fmaf(d1 * rs, ln1w[lane + 64],  ln1b[lane + 64]));
      cn[c][k][lane + 128] = bfu(fmaf(d2 * rs, ln1w[lane + 128], ln1b[lane + 128]));
      cn[c][k][lane + 192] = bfu(fmaf(d3 * rs, ln1w[lane + 192], ln1b[lane + 192]));
    }
  }
  __syncthreads();

  const int r16 = lane & 15;
  const int kg  = lane >> 4;
  const int c0 = (2 * wv) * 16 + r16;
  const int c1 = (2 * wv + 1) * 16 + r16;

  // GEMM1: reads cn into regs
  f32x4 a0[2] = {{0.f,0.f,0.f,0.f},{0.f,0.f,0.f,0.f}};
  f32x4 a1[2] = {{0.f,0.f,0.f,0.f},{0.f,0.f,0.f,0.f}};
#pragma unroll
  for (int kt = 0; kt < 8; kt++) {
    int k0 = kt * 32 + kg * 8;
    bf16x8 g0 = *(const bf16x8*)&Wt1[(size_t)c0 * 256 + k0];
    bf16x8 g1 = *(const bf16x8*)&Wt1[(size_t)c1 * 256 + k0];
#pragma unroll
    for (int c = 0; c < 2; c++) {
      bf16x8 af = *(const bf16x8*)&cn[c][r16][k0];
      a0[c] = __builtin_amdgcn_mfma_f32_16x16x32_bf16(af, g0, a0[c], 0, 0, 0);
      a1[c] = __builtin_amdgcn_mfma_f32_16x16x32_bf16(af, g1, a1[c], 0, 0, 0);
    }
  }
  __syncthreads();   // ALL cn reads complete before hb overwrites the pool
#pragma unroll
  for (int c = 0; c < 2; c++)
#pragma unroll
    for (int r = 0; r < 4; r++) {
      int ro = kg * 4 + r;
      hb[c][ro][c0] = bfu(fmaxf(a0[c][r] + b1[c0], 0.f));
      hb[c][ro][c1] = bfu(fmaxf(a1[c][r] + b1[c1], 0.f));
    }
  __syncthreads();

  // GEMM2: reads hb, writes wbb (disjoint from hb; overlaps dead cn)
  f32x4 s0[2] = {{0.f,0.f,0.f,0.f},{0.f,0.f,0.f,0.f}};
  f32x4 s1[2] = {{0.f,0.f,0.f,0.f},{0.f,0.f,0.f,0.f}};
#pragma unroll
  for (int kt = 0; kt < 4; kt++) {
    int k0 = kt * 32 + kg * 8;
    bf16x8 g0 = *(const bf16x8*)&Wt2[(size_t)c0 * 128 + k0];
    bf16x8 g1 = *(const bf16x8*)&Wt2[(size_t)c1 * 128 + k0];
#pragma unroll
    for (int c = 0; c < 2; c++) {
      bf16x8 af = *(const bf16x8*)&hb[c][r16][k0];
      s0[c] = __builtin_amdgcn_mfma_f32_16x16x32_bf16(af, g0, s0[c], 0, 0, 0);
      s1[c] = __builtin_amdgcn_mfma_f32_16x16x32_bf16(af, g1, s1[c], 0, 0, 0);
    }
  }
#pragma unroll
  for (int c = 0; c < 2; c++)
#pragma unroll
    for (int r = 0; r < 4; r++) {
      int ro = kg * 4 + r;
      wbb[c][ro][c0] = bfu(1.0f / (1.0f + expf(-(s0[c][r] + b2[c0]))));
      wbb[c][ro][c1] = bfu(1.0f / (1.0f + expf(-(s1[c][r] + b2[c1]))));
    }
  __syncthreads();

  {
    int c = tid >> 7, col = tid & 127;
    float ssum = 0.f;
#pragma unroll
    for (int kq = 0; kq < 16; kq++)
      ssum = fmaf(b2f(nb[c][kq][col]), b2f(wbb[c][kq][col]), ssum);
    float wmean = ssum * (1.0f / 16.0f);
    fvb[c][col] = bfu(fmaf(res_scale[0], wmean, cf[c][col]));
  }
  __syncthreads();

#pragma unroll
  for (int i = 0; i < 4; i++) {
    int cb = (wv * 4 + i) * 16;
    f32x4 acc[2] = {{0.f,0.f,0.f,0.f},{0.f,0.f,0.f,0.f}};
#pragma unroll
    for (int kt = 0; kt < 4; kt++) {
      int k0 = kt * 32 + kg * 8;
      bf16x8 gf = *(const bf16x8*)&Wtm[(size_t)(cb + r16) * 128 + k0];
#pragma unroll
      for (int c = 0; c < 2; c++) {
        bf16x8 af = *(const bf16x8*)&fvb[c][k0];
        acc[c] = __builtin_amdgcn_mfma_f32_16x16x32_bf16(af, gf, acc[c], 0, 0, 0);
      }
    }
    if (kg == 0) {
      int cc = cb + r16;
#pragma unroll
      for (int c = 0; c < 2; c++)
        outb[c][cc] = fmaxf(acc[c][0] + bm[cc], 0.f);
    }
  }
  __syncthreads();

  for (int c = 0; c < 2; c++) {
    float outx = outb[c][tid];
    float s = outx;
#pragma unroll
    for (int off = 1; off < 64; off <<= 1) s += __shfl_xor(s, off, 64);
    if (lane == 0) red[wv] = s;
    __syncthreads();
    float mu = (red[0] + red[1] + red[2] + red[3]) * (1.0f / 256.0f);
    float d = outx - mu;
    float s2 = d * d;
#pragma unroll
    for (int off = 1; off < 64; off <<= 1) s2 += __shfl_xor(s2, off, 64);
    __syncthreads();
    if (lane == 0) red[wv] = s2;
    __syncthreads();
    float var = (red[0] + red[1] + red[2] + red[3]) * (1.0f / 256.0f);
    float rs2 = 1.0f / __fsqrt_rn(var + LN_EPS_F);
    dout[(size_t)(cm0 + c) * OUT_ + tid] = fmaf(d * rs2, ln2w[tid], ln2b[tid]);
    __syncthreads();
  }
}

// ---------------------------------------------------------------------------
extern "C" void kernel_launch(void* const* d_in, const int* in_sizes, int n_in,
                              void* d_out, int out_size, void* d_ws, size_t ws_size,
                              hipStream_t stream) {
  const float* points = (const float*)d_in[0];
  const float* feats  = (const float*)d_in[1];
  const int*   cidx   = (const int*)  d_in[2];
  const float* ln1w   = (const float*)d_in[3];
  const float* ln1b   = (const float*)d_in[4];
  const float* W1     = (const float*)d_in[5];
  const float* b1     = (const float*)d_in[6];
  const float* W2     = (const float*)d_in[7];
  const float* b2     = (const float*)d_in[8];
  const float* Wm     = (const float*)d_in[9];
  const float* bm     = (const float*)d_in[10];
  const float* ln2w   = (const float*)d_in[11];
  const float* ln2b   = (const float*)d_in[12];
  const float* rscale = (const float*)d_in[13];

  float* out = (float*)d_out;
  char*  ws  = (char*)d_ws;
  float* pvals = (float*)ws;
  int*   pidx  = (int*)(ws + 16777216);
  int*   kidx  = (int*)(ws + 33554432);
  unsigned short* Wt1 = (unsigned short*)(ws + 34603008);
  unsigned short* Wt2 = (unsigned short*)(ws + 34603008 + 65536);
  unsigned short* Wtm = (unsigned short*)(ws + 34603008 + 65536 + 32768);

  convert_weights_kernel<<<(128 * 256 + 128 * 128 + 256 * 128 + TPB - 1) / TPB,
                           TPB, 0, stream>>>(W1, W2, Wm, Wt1, Wt2, Wtm);
  knn_partial_kernel<<<dim3(S_CHUNKS, M_ / TPB, B_), TPB, 0, stream>>>(points, cidx, pvals, pidx);
  knn_merge_kernel<<<BM / 64, 64, 0, stream>>>(pvals, pidx, kidx, out);
  fuse_mlp_kernel<<<BM / 2, TPB, 0, stream>>>(feats, cidx, kidx,
                                              ln1w, ln1b, Wt1, b1, Wt2, b2, Wtm, bm,
                                              ln2w, ln2b, rscale, out);
}